// Round 4
// baseline (90.949 us; speedup 1.0000x reference)
//
#include <hip/hip_runtime.h>

// QuantizationLayer: 3-bit successive-approximation soft ADC.
// Outputs flat: q [la], Q [la*3] (innermost dim = bit), Wn [6].
// R1: 149us @ 3.37 TB/s -- stride-48B Q stores uncoalesced.
// R2: 90.5us @ 5.56 TB/s -- LDS-staged coalesced Q stores.
// R3: wave-local LDS staging (no __syncthreads) + nontemporal streams.
//     (float4 is a HIP class -> use clang ext_vector for the builtins.)

typedef float fx4 __attribute__((ext_vector_type(4)));

__device__ __forceinline__ float fast_tanh(float z) {
    // tanh(z) = 1 - 2/(exp(2z)+1); saturates correctly at +/-inf.
    float e = __expf(2.0f * z);
    return 1.0f - 2.0f / (e + 1.0f);
}

__global__ void __launch_bounds__(256)
quant_kernel(const float* __restrict__ x,
             const float* __restrict__ W,
             const float* __restrict__ nz,
             float* __restrict__ out,
             int la /* = L*NUM_ADCS */) {
    __shared__ float lds[3072];  // 12 KB; wave w owns lds[768w .. 768w+768)

    // Wn scalars — same-address broadcast loads.
    const float wn0 = W[0] + nz[0];
    const float wn1 = W[1] + nz[1];
    const float wn2 = W[2] + nz[2];
    const float wn3 = W[3] + nz[3];
    const float wn4 = W[4] + nz[4];
    const float wn5 = W[5] + nz[5];

    const float VR  = 0.225f;
    const float AMP = 10000.0f;
    const float DLT = 1e-30f;
    const float s2  = wn5 * VR;
    const float b1  = wn4 * VR;
    const float a1  = 0.5f * wn3 * VR;
    const float b0  = wn2 * VR;
    const float a01 = 0.5f * wn1 * VR;
    const float a02 = 0.5f * wn0 * VR;
    const float w0  = 0.5f * VR;
    const float w1  = VR;
    const float w2  = 2.0f * VR;

    const int  t    = threadIdx.x;
    const int  w    = t >> 6;          // wave id 0..3
    const int  l    = t & 63;          // lane id
    const long base = (long)blockIdx.x * 1024;
    float* __restrict__ Qout = out + (long)la;

    if (base + 1024 <= (long)la) {
        // ---- fast path: full 1024-element chunk ----
        const fx4 xv = __builtin_nontemporal_load(
            reinterpret_cast<const fx4*>(x + base) + t);
        float q[4], Qv[12];
        #pragma unroll
        for (int k = 0; k < 4; ++k) {
            const float xe = xv[k];
            const float Q2 = fast_tanh(AMP * (xe - s2 + DLT));
            const float Q1 = fast_tanh(AMP * (xe - (b1 + (Q2 + 1.0f) * a1) + DLT));
            const float Q0 = fast_tanh(AMP * (xe - (b0 + (Q1 + 1.0f) * a01
                                                       + (Q2 + 1.0f) * a02) + DLT));
            q[k] = (Q0 + 1.0f) * w0 + (Q1 + 1.0f) * w1 + (Q2 + 1.0f) * w2;
            Qv[k * 3 + 0] = Q0;
            Qv[k * 3 + 1] = Q1;
            Qv[k * 3 + 2] = Q2;
        }
        const fx4 qv = {q[0], q[1], q[2], q[3]};
        __builtin_nontemporal_store(qv, reinterpret_cast<fx4*>(out + base) + t);

        // Wave-local LDS staging: lane l writes 48B at lds[768w + 12l]
        // (12l mod 32 covers all banks -> conflict-free).
        fx4* lp = reinterpret_cast<fx4*>(&lds[t * 12]);
        lp[0] = (fx4){Qv[0], Qv[1], Qv[2],  Qv[3]};
        lp[1] = (fx4){Qv[4], Qv[5], Qv[6],  Qv[7]};
        lp[2] = (fx4){Qv[8], Qv[9], Qv[10], Qv[11]};
        // No __syncthreads: each wave reads back only its own region; the
        // compiler's lgkmcnt ordering covers the within-wave RAW hazard.

        // Coalesced Q writes: wave w writes its 192 contiguous 16B words.
        fx4* __restrict__ Qg =
            reinterpret_cast<fx4*>(Qout + base * 3) + w * 192;
        const fx4* ls = reinterpret_cast<const fx4*>(&lds[w * 768]);
        __builtin_nontemporal_store(ls[l],       Qg + l);
        __builtin_nontemporal_store(ls[l + 64],  Qg + l + 64);
        __builtin_nontemporal_store(ls[l + 128], Qg + l + 128);
    } else {
        // ---- tail path: per-element guarded (not hit at la=25165824) ----
        for (int k = 0; k < 4; ++k) {
            const long e = base + t * 4 + k;
            if (e >= (long)la) break;
            const float xe = x[e];
            const float Q2 = fast_tanh(AMP * (xe - s2 + DLT));
            const float Q1 = fast_tanh(AMP * (xe - (b1 + (Q2 + 1.0f) * a1) + DLT));
            const float Q0 = fast_tanh(AMP * (xe - (b0 + (Q1 + 1.0f) * a01
                                                       + (Q2 + 1.0f) * a02) + DLT));
            out[e] = (Q0 + 1.0f) * w0 + (Q1 + 1.0f) * w1 + (Q2 + 1.0f) * w2;
            Qout[e * 3 + 0] = Q0;
            Qout[e * 3 + 1] = Q1;
            Qout[e * 3 + 2] = Q2;
        }
    }

    // Wn passthrough output: 6 floats at tail of out.
    if (blockIdx.x == 0 && t < 6) {
        out[(long)la * 4 + t] = W[t] + nz[t];
    }
}

extern "C" void kernel_launch(void* const* d_in, const int* in_sizes, int n_in,
                              void* d_out, int out_size, void* d_ws, size_t ws_size,
                              hipStream_t stream) {
    const float* x  = (const float*)d_in[0];
    const float* W  = (const float*)d_in[1];
    const float* nz = (const float*)d_in[2];
    float* out = (float*)d_out;
    const int la = in_sizes[0];            // 25165824

    const int block = 256;
    const int grid = (la + 1023) / 1024;   // 24576 blocks: 1024 elems each
    quant_kernel<<<grid, block, 0, stream>>>(x, W, nz, out, la);
}